// Round 2
// baseline (12.567 us; speedup 1.0000x reference)
//
#include <hip/hip_runtime.h>
#include <hip/hip_bf16.h>

// Cross-entropy loss: out = -mean_i log(pred[i, label[i]])
// pred: [B, C] float32, label: [B] int32, out: scalar f32.
// Only B gathered elements of pred are needed. Spread the B scattered line
// fetches across many CUs (1 row/thread, 128 blocks x 64 threads) so no
// single CU serializes the ~1 MB of cache-line traffic. Combine with one
// float atomicAdd per block into d_out (zeroed via async memset each call).

__global__ __launch_bounds__(64)
void ce_gather_log_mean(const float* __restrict__ pred,
                        const int* __restrict__ label,
                        float* __restrict__ out,
                        int B, long long C) {
    const int i = blockIdx.x * 64 + threadIdx.x;

    float v = 0.0f;
    if (i < B) {
        const int lbl = label[i];                       // coalesced
        v = logf(pred[(long long)i * C + (long long)lbl]); // scattered, 1 line/lane
    }

    // 64-lane wave butterfly reduction (block == 1 wave).
    #pragma unroll
    for (int off = 32; off > 0; off >>= 1)
        v += __shfl_down(v, off, 64);

    if (threadIdx.x == 0)
        atomicAdd(out, -v / (float)B);   // 128 adds to one address, device-scope
}

extern "C" void kernel_launch(void* const* d_in, const int* in_sizes, int n_in,
                              void* d_out, int out_size, void* d_ws, size_t ws_size,
                              hipStream_t stream) {
    const float* pred  = (const float*)d_in[0];
    const int*   label = (const int*)d_in[1];
    float*       out   = (float*)d_out;

    const int B = in_sizes[1];
    const long long C = (long long)in_sizes[0] / (long long)B;

    // Deterministic re-init: harness poisons d_out once, not between replays.
    hipMemsetAsync(out, 0, sizeof(float), stream);

    const int blocks = (B + 63) / 64;   // 128 blocks for B=8192
    ce_gather_log_mean<<<blocks, 64, 0, stream>>>(pred, label, out, B, C);
}